// Round 4
// baseline (121.525 us; speedup 1.0000x reference)
//
#include <hip/hip_runtime.h>
#include <hip/hip_bf16.h>
#include <stdint.h>

#define B_   512
#define C_   440
#define CR_  52
#define HW_  49
#define KP_  448          // padded K (=C) to multiple of 32 (= 7*64)
#define OP_  512          // padded O (=C) to multiple of 128
#define M_   25088        // B_*HW_ (= 196*128 exactly)
#define CCH_ 64           // c-chunk per scatter block
#define TSS_ 72           // scatter LDS row stride (shorts)

typedef __attribute__((ext_vector_type(8))) short bf8;
typedef __attribute__((ext_vector_type(4))) float f4;

__device__ __forceinline__ unsigned short f2bf(float f) {
  union { float f; unsigned u; } v; v.f = f;
  unsigned r = v.u + 0x7FFFu + ((v.u >> 16) & 1u);
  return (unsigned short)(r >> 16);
}

__device__ __forceinline__ void gld16(const void* g, void* l) {
  __builtin_amdgcn_global_load_lds(
      (const __attribute__((address_space(1))) unsigned int*)g,
      (__attribute__((address_space(3))) unsigned int*)l, 16, 0, 0);
}

// ---------------- K1: w3 fp32 -> bf16, padded [OP_][KP_] ----------------
__global__ __launch_bounds__(256) void k_prep_w3(const float* __restrict__ w3,
                                                 unsigned short* __restrict__ w3bf) {
  int idx = blockIdx.x * 256 + threadIdx.x;      // grid covers 512*448 exactly
  int o = idx / KP_, c = idx - o * KP_;
  float v = (c < C_ && o < C_) ? w3[o * C_ + c] : 0.f;
  w3bf[idx] = f2bf(v);
}

// ---------------- K2a: per-b gate MLP -> gate[b][c] fp32 ----------------
__global__ __launch_bounds__(256) void k_gate(
    const float* __restrict__ x178,
    const float* __restrict__ w1, const float* __restrict__ b1,
    const float* __restrict__ w2, const float* __restrict__ b2,
    float* __restrict__ gate) {
  __shared__ float s_s[C_];
  __shared__ float s_h[CR_];
  int b = blockIdx.x, tid = threadIdx.x;
  int g = tid >> 4, l16 = tid & 15;   // 16 groups of 16 lanes

  for (int c = tid; c < C_; c += 256) s_s[c] = x178[b * C_ + c];
  __syncthreads();

  // h = relu(s @ w1^T + b1): one 16-lane group per row
  for (int r = g; r < CR_; r += 16) {
    float acc = 0.f;
    for (int c = l16; c < C_; c += 16) acc += s_s[c] * w1[r * C_ + c];
    #pragma unroll
    for (int off = 8; off; off >>= 1) acc += __shfl_xor(acc, off, 64);
    if (l16 == 0) s_h[r] = fmaxf(acc + b1[r], 0.f);
  }
  __syncthreads();

  // gate = sigmoid(h @ w2^T + b2)
  for (int c = tid; c < C_; c += 256) {
    float acc = b2[c];
    #pragma unroll 4
    for (int r = 0; r < CR_; ++r) acc += s_h[r] * w2[c * CR_ + r];
    gate[b * C_ + c] = 1.f / (1.f + __expf(-acc));
  }
}

// ------- K2b: gating + bf16 + transpose, one block per (c-chunk, b) -------
__global__ __launch_bounds__(256) void k_scatter(
    const float* __restrict__ x177, const float* __restrict__ gate,
    unsigned short* __restrict__ gbf) {
  __shared__ __align__(16) unsigned short s_t[HW_ * TSS_];  // [49][72] bf16
  __shared__ float s_g[CCH_];
  int cc = blockIdx.x, b = blockIdx.y, tid = threadIdx.x;
  int c0 = cc * CCH_;
  int valid_c = (c0 + CCH_ <= C_) ? CCH_ : (C_ - c0);   // 64 or 56 (chunk 6)

  // zero-init tile (covers K-pad cols) + load gate slice
  unsigned* zt = (unsigned*)s_t;
  for (int i = tid; i < HW_ * TSS_ / 2; i += 256) zt[i] = 0u;
  if (tid < CCH_) {
    int c = c0 + tid;
    s_g[tid] = (c < C_) ? gate[b * C_ + c] : 0.f;
  }
  __syncthreads();

  // read contiguous fp32 slab x177[b][c0 : c0+valid_c][0:49], gate, write LDS
  const f4* xp = (const f4*)(x177 + (size_t)b * (C_ * HW_) + (size_t)c0 * HW_);
  int nvec = valid_c * HW_ / 4;   // 784 or 686 (both exact)
  for (int it = 0; it < 4; ++it) {
    int idx = it * 256 + tid;
    if (idx < nvec) {
      f4 v = xp[idx];
      int e = idx * 4;
      #pragma unroll
      for (int j = 0; j < 4; ++j) {
        int ej = e + j;
        int cl = ej / HW_, hw = ej - cl * HW_;
        s_t[hw * TSS_ + cl] = f2bf(v[j] * s_g[cl]);
      }
    }
  }
  __syncthreads();

  // write out gbf[(b*49+hw)][c0 + cg*8], 16B chunks
  unsigned short* gp = gbf + (size_t)b * HW_ * KP_ + c0;
  for (int it = 0; it < 2; ++it) {
    int p = it * 256 + tid;
    if (p < HW_ * (CCH_ / 8)) {
      int hw = p >> 3, cg = p & 7;
      *(bf8*)(gp + hw * KP_ + cg * 8) = *(const bf8*)(s_t + hw * TSS_ + cg * 8);
    }
  }
}

// ---------------- K3: y[o][m] = sum_c w3[o][c] * g[m][c]  (bf16 MFMA) ----------------
__global__ __launch_bounds__(256) void k_gemm(const unsigned short* __restrict__ w3bf,
                                              const unsigned short* __restrict__ gbf,
                                              float* __restrict__ y) {
  __shared__ __align__(16) unsigned short lds[2 * 128 * 32];  // A tile | B tile
  int tid = threadIdx.x, lane = tid & 63, wv = tid >> 6;
  int bid = blockIdx.x;
  int o0 = (bid & 3) * 128;        // 4 o-tiles (OP_=512)
  int m0 = (bid >> 2) * 128;       // 196 m-tiles
  int wr = wv >> 1, wc = wv & 1;   // wave -> 64x64 quadrant
  f4 acc[4][4] = {};
  const char* Ab = (const char*)w3bf;  // row stride 896 B
  const char* Bb = (const char*)gbf;   // row stride 896 B
  int q0 = wv * 64 + lane;

  for (int kt = 0; kt < KP_ / 32; ++kt) {
    int k0b = kt * 64;  // byte offset of k0 within a row
    #pragma unroll
    for (int i = 0; i < 2; ++i) {
      int q = q0 + i * 256;
      int r = q >> 2, cc = (q & 3) * 16;
      gld16(Ab + (size_t)(o0 + r) * 896 + k0b + cc,
            (char*)lds + (wv * 64 + i * 256) * 16);
      gld16(Bb + (size_t)(m0 + r) * 896 + k0b + cc,
            (char*)lds + 8192 + (wv * 64 + i * 256) * 16);
    }
    __syncthreads();   // compiler drains vmcnt before barrier

    bf8 a[4], bb[4];
    int kg = (lane >> 4) * 8, rl = lane & 15;
    #pragma unroll
    for (int i = 0; i < 4; ++i)
      a[i] = *(const bf8*)(lds + (wr * 64 + i * 16 + rl) * 32 + kg);
    #pragma unroll
    for (int j = 0; j < 4; ++j)
      bb[j] = *(const bf8*)(lds + 4096 + (wc * 64 + j * 16 + rl) * 32 + kg);
    #pragma unroll
    for (int i = 0; i < 4; ++i)
      #pragma unroll
      for (int j = 0; j < 4; ++j)
        acc[i][j] = __builtin_amdgcn_mfma_f32_16x16x32_bf16(a[i], bb[j], acc[i][j], 0, 0, 0);
    __syncthreads();
  }

  // D layout: col = lane&15 (m), row = (lane>>4)*4 + reg (o)
  int col = lane & 15, r4 = (lane >> 4) * 4;
  #pragma unroll
  for (int i = 0; i < 4; ++i) {
    int ob = o0 + wr * 64 + i * 16 + r4;
    #pragma unroll
    for (int j = 0; j < 4; ++j) {
      int m = m0 + wc * 64 + j * 16 + col;
      #pragma unroll
      for (int r = 0; r < 4; ++r) {
        int o = ob + r;
        if (o < C_) y[(size_t)o * M_ + m] = acc[i][j][r];
      }
    }
  }
}

// ---------------- K4: per-channel mean/var + normalize + scatter ----------------
__global__ __launch_bounds__(256) void k_norm(const float* __restrict__ y,
                                              const float* __restrict__ gamma,
                                              const float* __restrict__ beta,
                                              float* __restrict__ out) {
  __shared__ float rs[4], rq[4];
  __shared__ float s_scale, s_shift;
  int o = blockIdx.x, tid = threadIdx.x, lane = tid & 63, wv = tid >> 6;
  const float4* yr = (const float4*)(y + (size_t)o * M_);
  float sum = 0.f, sq = 0.f;
  for (int i = tid; i < M_ / 4; i += 256) {
    float4 v = yr[i];
    sum += v.x + v.y + v.z + v.w;
    sq  += v.x * v.x + v.y * v.y + v.z * v.z + v.w * v.w;
  }
  #pragma unroll
  for (int off = 32; off; off >>= 1) {
    sum += __shfl_xor(sum, off, 64);
    sq  += __shfl_xor(sq,  off, 64);
  }
  if (lane == 0) { rs[wv] = sum; rq[wv] = sq; }
  __syncthreads();
  if (tid == 0) {
    float S = rs[0] + rs[1] + rs[2] + rs[3];
    float Q = rq[0] + rq[1] + rq[2] + rq[3];
    float mean = S / (float)M_;
    float var  = Q / (float)M_ - mean * mean;
    float sc = gamma[o] * rsqrtf(var + 1e-5f);
    s_scale = sc;
    s_shift = beta[o] - mean * sc;
  }
  __syncthreads();
  float sc = s_scale, sh = s_shift;
  for (int i = tid; i < M_ / 4; i += 256) {
    float4 v = yr[i];
    float vals[4] = {v.x * sc + sh, v.y * sc + sh, v.z * sc + sh, v.w * sc + sh};
    int m = i * 4;
    #pragma unroll
    for (int j = 0; j < 4; ++j) {
      int mm = m + j;
      int bb = mm / HW_, hw = mm - bb * HW_;
      out[(size_t)bb * (C_ * HW_) + o * HW_ + hw] = vals[j];
    }
  }
}

extern "C" void kernel_launch(void* const* d_in, const int* in_sizes, int n_in,
                              void* d_out, int out_size, void* d_ws, size_t ws_size,
                              hipStream_t stream) {
  const float* x178 = (const float*)d_in[0];
  const float* x177 = (const float*)d_in[1];
  const float* w1   = (const float*)d_in[2];
  const float* b1   = (const float*)d_in[3];
  const float* w2   = (const float*)d_in[4];
  const float* b2   = (const float*)d_in[5];
  const float* w3   = (const float*)d_in[6];
  const float* gamma= (const float*)d_in[7];
  const float* beta = (const float*)d_in[8];
  float* out = (float*)d_out;

  char* ws = (char*)d_ws;
  unsigned short* w3bf = (unsigned short*)ws;                        // 512*448*2 = 458752
  unsigned short* gbf  = (unsigned short*)(ws + 458752);             // 25088*448*2 = 22478848
  float* y             = (float*)(ws + 458752 + 22478848);           // 440*25088*4 = 44154880
  float* gate          = y;   // 512*440*4 = 901120 B, head of y region;
                              // consumed by k_scatter before k_gemm overwrites y

  hipLaunchKernelGGL(k_prep_w3, dim3((OP_ * KP_) / 256), dim3(256), 0, stream, w3, w3bf);
  hipLaunchKernelGGL(k_gate, dim3(B_), dim3(256), 0, stream,
                     x178, w1, b1, w2, b2, gate);
  hipLaunchKernelGGL(k_scatter, dim3(KP_ / CCH_, B_), dim3(256), 0, stream,
                     x177, gate, gbf);
  hipLaunchKernelGGL(k_gemm, dim3((M_ / 128) * (OP_ / 128)), dim3(256), 0, stream,
                     w3bf, gbf, y);
  hipLaunchKernelGGL(k_norm, dim3(C_), dim3(256), 0, stream, y, gamma, beta, out);
}

// Round 5
// 91.530 us; speedup vs baseline: 1.3277x; 1.3277x over previous
//
#include <hip/hip_runtime.h>
#include <hip/hip_bf16.h>
#include <stdint.h>

#define B_   512
#define C_   440
#define CR_  52
#define HW_  49
#define KP_  448          // padded K (=C) to multiple of 32 (= 7*64)
#define OP_  512          // padded O (=C) to multiple of 128
#define M_   25088        // B_*HW_ (= 196*128 exactly)
#define CCH_ 64           // c-chunk per scatter block
#define TSS_ 72           // scatter LDS row stride (shorts)

typedef __attribute__((ext_vector_type(8))) short bf8;
typedef __attribute__((ext_vector_type(4))) float f4;

__device__ __forceinline__ unsigned short f2bf(float f) {
  union { float f; unsigned u; } v; v.f = f;
  unsigned r = v.u + 0x7FFFu + ((v.u >> 16) & 1u);
  return (unsigned short)(r >> 16);
}

__device__ __forceinline__ void gld16(const void* g, void* l) {
  __builtin_amdgcn_global_load_lds(
      (const __attribute__((address_space(1))) unsigned int*)g,
      (__attribute__((address_space(3))) unsigned int*)l, 16, 0, 0);
}

// ---------------- K1: w3 fp32 -> bf16, padded [OP_][KP_] ----------------
__global__ __launch_bounds__(256) void k_prep_w3(const float* __restrict__ w3,
                                                 unsigned short* __restrict__ w3bf) {
  int idx = blockIdx.x * 256 + threadIdx.x;      // grid covers 512*448 exactly
  int o = idx / KP_, c = idx - o * KP_;
  float v = (c < C_ && o < C_) ? w3[o * C_ + c] : 0.f;
  w3bf[idx] = f2bf(v);
}

// ---------------- K2a: per-b gate MLP -> gate[b][c] fp32 ----------------
// Phase A: thread t=4r+q -> h[r] via float4 quarter-rows (fully unrolled loads)
// Phase B: thread per c -> sigmoid(dot(h, w2[c])) via float4
__global__ __launch_bounds__(256) void k_gate(
    const float* __restrict__ x178,
    const float* __restrict__ w1, const float* __restrict__ b1,
    const float* __restrict__ w2, const float* __restrict__ b2,
    float* __restrict__ gate) {
  __shared__ __align__(16) float s_s[C_];
  __shared__ __align__(16) float s_h[CR_ + 12];   // padded to 64 floats (16 f4)
  int b = blockIdx.x, tid = threadIdx.x;

  if (tid < C_ / 4) ((f4*)s_s)[tid] = ((const f4*)(x178 + (size_t)b * C_))[tid];
  if (tid >= 240 && tid < 240 + 16) ((f4*)s_h)[tid - 240] = f4{0.f, 0.f, 0.f, 0.f};
  __syncthreads();

  int r = tid >> 2, q = tid & 3;     // 64 rows x 4 threads (rows 52..63 idle)
  if (r < CR_) {
    const f4* wr = (const f4*)(w1 + (size_t)r * C_);   // 110 f4 per row
    const f4* ss = (const f4*)s_s;
    f4 acc = {0.f, 0.f, 0.f, 0.f};
    #pragma unroll
    for (int j0 = 0; j0 < 28; ++j0) {
      int j = q + j0 * 4;
      if (j < C_ / 4) {
        f4 w = wr[j], x = ss[j];
        acc += w * x;
      }
    }
    float a = acc[0] + acc[1] + acc[2] + acc[3];
    a += __shfl_xor(a, 1, 64);
    a += __shfl_xor(a, 2, 64);
    if (q == 0) s_h[r] = fmaxf(a + b1[r], 0.f);
  }
  __syncthreads();

  for (int c = tid; c < C_; c += 256) {
    const f4* wc = (const f4*)(w2 + (size_t)c * CR_);  // 13 f4 per row
    const f4* hh = (const f4*)s_h;
    f4 acc = {0.f, 0.f, 0.f, 0.f};
    #pragma unroll
    for (int j = 0; j < 13; ++j) acc += wc[j] * hh[j];
    float a = acc[0] + acc[1] + acc[2] + acc[3] + b2[c];
    gate[b * C_ + c] = 1.f / (1.f + __expf(-a));
  }
}

// ------- K2b: gating + bf16 + transpose, one block per (c-chunk, b) -------
__global__ __launch_bounds__(256) void k_scatter(
    const float* __restrict__ x177, const float* __restrict__ gate,
    unsigned short* __restrict__ gbf) {
  __shared__ __align__(16) unsigned short s_t[HW_ * TSS_];  // [49][72] bf16
  __shared__ float s_g[CCH_];
  int cc = blockIdx.x, b = blockIdx.y, tid = threadIdx.x;
  int c0 = cc * CCH_;
  int valid_c = (c0 + CCH_ <= C_) ? CCH_ : (C_ - c0);   // 64 or 56 (chunk 6)

  // zero-init tile (covers K-pad cols) + load gate slice
  unsigned* zt = (unsigned*)s_t;
  for (int i = tid; i < HW_ * TSS_ / 2; i += 256) zt[i] = 0u;
  if (tid < CCH_) {
    int c = c0 + tid;
    s_g[tid] = (c < C_) ? gate[b * C_ + c] : 0.f;
  }
  __syncthreads();

  // read contiguous fp32 slab x177[b][c0 : c0+valid_c][0:49], gate, write LDS
  const f4* xp = (const f4*)(x177 + (size_t)b * (C_ * HW_) + (size_t)c0 * HW_);
  int nvec = valid_c * HW_ / 4;   // 784 or 686 (both exact)
  for (int it = 0; it < 4; ++it) {
    int idx = it * 256 + tid;
    if (idx < nvec) {
      f4 v = xp[idx];
      int e = idx * 4;
      #pragma unroll
      for (int j = 0; j < 4; ++j) {
        int ej = e + j;
        int cl = ej / HW_, hw = ej - cl * HW_;
        s_t[hw * TSS_ + cl] = f2bf(v[j] * s_g[cl]);
      }
    }
  }
  __syncthreads();

  // write out gbf[(b*49+hw)][c0 + cg*8], 16B chunks
  unsigned short* gp = gbf + (size_t)b * HW_ * KP_ + c0;
  for (int it = 0; it < 2; ++it) {
    int p = it * 256 + tid;
    if (p < HW_ * (CCH_ / 8)) {
      int hw = p >> 3, cg = p & 7;
      *(bf8*)(gp + hw * KP_ + cg * 8) = *(const bf8*)(s_t + hw * TSS_ + cg * 8);
    }
  }
}

// ---------------- K3: y[o][m] = sum_c w3[o][c] * g[m][c]  (bf16 MFMA) ----------------
__global__ __launch_bounds__(256) void k_gemm(const unsigned short* __restrict__ w3bf,
                                              const unsigned short* __restrict__ gbf,
                                              float* __restrict__ y) {
  __shared__ __align__(16) unsigned short lds[2 * 128 * 32];  // A tile | B tile
  int tid = threadIdx.x, lane = tid & 63, wv = tid >> 6;
  int bid = blockIdx.x;
  int o0 = (bid & 3) * 128;        // 4 o-tiles (OP_=512)
  int m0 = (bid >> 2) * 128;       // 196 m-tiles
  int wr = wv >> 1, wc = wv & 1;   // wave -> 64x64 quadrant
  f4 acc[4][4] = {};
  const char* Ab = (const char*)w3bf;  // row stride 896 B
  const char* Bb = (const char*)gbf;   // row stride 896 B
  int q0 = wv * 64 + lane;

  for (int kt = 0; kt < KP_ / 32; ++kt) {
    int k0b = kt * 64;  // byte offset of k0 within a row
    #pragma unroll
    for (int i = 0; i < 2; ++i) {
      int q = q0 + i * 256;
      int r = q >> 2, cc = (q & 3) * 16;
      gld16(Ab + (size_t)(o0 + r) * 896 + k0b + cc,
            (char*)lds + (wv * 64 + i * 256) * 16);
      gld16(Bb + (size_t)(m0 + r) * 896 + k0b + cc,
            (char*)lds + 8192 + (wv * 64 + i * 256) * 16);
    }
    __syncthreads();   // compiler drains vmcnt before barrier

    bf8 a[4], bb[4];
    int kg = (lane >> 4) * 8, rl = lane & 15;
    #pragma unroll
    for (int i = 0; i < 4; ++i)
      a[i] = *(const bf8*)(lds + (wr * 64 + i * 16 + rl) * 32 + kg);
    #pragma unroll
    for (int j = 0; j < 4; ++j)
      bb[j] = *(const bf8*)(lds + 4096 + (wc * 64 + j * 16 + rl) * 32 + kg);
    #pragma unroll
    for (int i = 0; i < 4; ++i)
      #pragma unroll
      for (int j = 0; j < 4; ++j)
        acc[i][j] = __builtin_amdgcn_mfma_f32_16x16x32_bf16(a[i], bb[j], acc[i][j], 0, 0, 0);
    __syncthreads();
  }

  // D layout: col = lane&15 (m), row = (lane>>4)*4 + reg (o)
  int col = lane & 15, r4 = (lane >> 4) * 4;
  #pragma unroll
  for (int i = 0; i < 4; ++i) {
    int ob = o0 + wr * 64 + i * 16 + r4;
    #pragma unroll
    for (int j = 0; j < 4; ++j) {
      int m = m0 + wc * 64 + j * 16 + col;
      #pragma unroll
      for (int r = 0; r < 4; ++r) {
        int o = ob + r;
        if (o < C_) y[(size_t)o * M_ + m] = acc[i][j][r];
      }
    }
  }
}

// ---------------- K4: per-channel mean/var + normalize + scatter ----------------
__global__ __launch_bounds__(256) void k_norm(const float* __restrict__ y,
                                              const float* __restrict__ gamma,
                                              const float* __restrict__ beta,
                                              float* __restrict__ out) {
  __shared__ float rs[4], rq[4];
  __shared__ float s_scale, s_shift;
  int o = blockIdx.x, tid = threadIdx.x, lane = tid & 63, wv = tid >> 6;
  const float4* yr = (const float4*)(y + (size_t)o * M_);
  float sum = 0.f, sq = 0.f;
  for (int i = tid; i < M_ / 4; i += 256) {
    float4 v = yr[i];
    sum += v.x + v.y + v.z + v.w;
    sq  += v.x * v.x + v.y * v.y + v.z * v.z + v.w * v.w;
  }
  #pragma unroll
  for (int off = 32; off; off >>= 1) {
    sum += __shfl_xor(sum, off, 64);
    sq  += __shfl_xor(sq,  off, 64);
  }
  if (lane == 0) { rs[wv] = sum; rq[wv] = sq; }
  __syncthreads();
  if (tid == 0) {
    float S = rs[0] + rs[1] + rs[2] + rs[3];
    float Q = rq[0] + rq[1] + rq[2] + rq[3];
    float mean = S / (float)M_;
    float var  = Q / (float)M_ - mean * mean;
    float sc = gamma[o] * rsqrtf(var + 1e-5f);
    s_scale = sc;
    s_shift = beta[o] - mean * sc;
  }
  __syncthreads();
  float sc = s_scale, sh = s_shift;
  for (int i = tid; i < M_ / 4; i += 256) {
    float4 v = yr[i];
    float vals[4] = {v.x * sc + sh, v.y * sc + sh, v.z * sc + sh, v.w * sc + sh};
    int m = i * 4;
    #pragma unroll
    for (int j = 0; j < 4; ++j) {
      int mm = m + j;
      int bb = mm / HW_, hw = mm - bb * HW_;
      out[(size_t)bb * (C_ * HW_) + o * HW_ + hw] = vals[j];
    }
  }
}

extern "C" void kernel_launch(void* const* d_in, const int* in_sizes, int n_in,
                              void* d_out, int out_size, void* d_ws, size_t ws_size,
                              hipStream_t stream) {
  const float* x178 = (const float*)d_in[0];
  const float* x177 = (const float*)d_in[1];
  const float* w1   = (const float*)d_in[2];
  const float* b1   = (const float*)d_in[3];
  const float* w2   = (const float*)d_in[4];
  const float* b2   = (const float*)d_in[5];
  const float* w3   = (const float*)d_in[6];
  const float* gamma= (const float*)d_in[7];
  const float* beta = (const float*)d_in[8];
  float* out = (float*)d_out;

  char* ws = (char*)d_ws;
  unsigned short* w3bf = (unsigned short*)ws;                        // 512*448*2 = 458752
  unsigned short* gbf  = (unsigned short*)(ws + 458752);             // 25088*448*2 = 22478848
  float* y             = (float*)(ws + 458752 + 22478848);           // 440*25088*4 = 44154880
  float* gate          = y;   // 512*440*4 = 901120 B, head of y region;
                              // consumed by k_scatter before k_gemm overwrites y

  hipLaunchKernelGGL(k_prep_w3, dim3((OP_ * KP_) / 256), dim3(256), 0, stream, w3, w3bf);
  hipLaunchKernelGGL(k_gate, dim3(B_), dim3(256), 0, stream,
                     x178, w1, b1, w2, b2, gate);
  hipLaunchKernelGGL(k_scatter, dim3(KP_ / CCH_, B_), dim3(256), 0, stream,
                     x177, gate, gbf);
  hipLaunchKernelGGL(k_gemm, dim3((M_ / 128) * (OP_ / 128)), dim3(256), 0, stream,
                     w3bf, gbf, y);
  hipLaunchKernelGGL(k_norm, dim3(C_), dim3(256), 0, stream, y, gamma, beta, out);
}

// Round 6
// 85.876 us; speedup vs baseline: 1.4151x; 1.0658x over previous
//
#include <hip/hip_runtime.h>
#include <hip/hip_bf16.h>
#include <stdint.h>

#define B_   512
#define C_   440
#define CR_  52
#define HW_  49
#define KP_  448          // padded K (=C) to multiple of 32 (= 7*64)
#define OP_  512          // padded O (=C) to multiple of 128
#define M_   25088        // B_*HW_ (= 196*128 exactly)
#define CCH_ 64           // c-chunk per scatter block
#define TSS_ 72           // scatter LDS row stride (shorts)
#define NT_  (KP_ / 32)   // 14 K-steps

typedef __attribute__((ext_vector_type(8))) short bf8;
typedef __attribute__((ext_vector_type(4))) float f4;

__device__ __forceinline__ unsigned short f2bf(float f) {
  union { float f; unsigned u; } v; v.f = f;
  unsigned r = v.u + 0x7FFFu + ((v.u >> 16) & 1u);
  return (unsigned short)(r >> 16);
}

__device__ __forceinline__ void gld16(const void* g, void* l) {
  __builtin_amdgcn_global_load_lds(
      (const __attribute__((address_space(1))) unsigned int*)g,
      (__attribute__((address_space(3))) unsigned int*)l, 16, 0, 0);
}

// ---------------- K1: w3 fp32 -> bf16, padded [OP_][KP_] ----------------
__global__ __launch_bounds__(256) void k_prep_w3(const float* __restrict__ w3,
                                                 unsigned short* __restrict__ w3bf) {
  int idx = blockIdx.x * 256 + threadIdx.x;      // grid covers 512*448 exactly
  int o = idx / KP_, c = idx - o * KP_;
  float v = (c < C_ && o < C_) ? w3[o * C_ + c] : 0.f;
  w3bf[idx] = f2bf(v);
}

// ---------------- K2a: per-b gate MLP -> gate[b][c] fp32 ----------------
__global__ __launch_bounds__(256) void k_gate(
    const float* __restrict__ x178,
    const float* __restrict__ w1, const float* __restrict__ b1,
    const float* __restrict__ w2, const float* __restrict__ b2,
    float* __restrict__ gate) {
  __shared__ __align__(16) float s_s[C_];
  __shared__ __align__(16) float s_h[CR_ + 12];   // padded to 64 floats (16 f4)
  int b = blockIdx.x, tid = threadIdx.x;

  if (tid < C_ / 4) ((f4*)s_s)[tid] = ((const f4*)(x178 + (size_t)b * C_))[tid];
  if (tid >= 240 && tid < 240 + 16) ((f4*)s_h)[tid - 240] = f4{0.f, 0.f, 0.f, 0.f};
  __syncthreads();

  int r = tid >> 2, q = tid & 3;     // 64 rows x 4 threads (rows 52..63 idle)
  if (r < CR_) {
    const f4* wr = (const f4*)(w1 + (size_t)r * C_);   // 110 f4 per row
    const f4* ss = (const f4*)s_s;
    f4 acc = {0.f, 0.f, 0.f, 0.f};
    #pragma unroll
    for (int j0 = 0; j0 < 28; ++j0) {
      int j = q + j0 * 4;
      if (j < C_ / 4) {
        f4 w = wr[j], x = ss[j];
        acc += w * x;
      }
    }
    float a = acc[0] + acc[1] + acc[2] + acc[3];
    a += __shfl_xor(a, 1, 64);
    a += __shfl_xor(a, 2, 64);
    if (q == 0) s_h[r] = fmaxf(a + b1[r], 0.f);
  }
  __syncthreads();

  for (int c = tid; c < C_; c += 256) {
    const f4* wc = (const f4*)(w2 + (size_t)c * CR_);  // 13 f4 per row
    const f4* hh = (const f4*)s_h;
    f4 acc = {0.f, 0.f, 0.f, 0.f};
    #pragma unroll
    for (int j = 0; j < 13; ++j) acc += wc[j] * hh[j];
    float a = acc[0] + acc[1] + acc[2] + acc[3] + b2[c];
    gate[b * C_ + c] = 1.f / (1.f + __expf(-a));
  }
}

// ------- K2b: gating + bf16 + transpose, one block per (c-chunk, b) -------
__global__ __launch_bounds__(256) void k_scatter(
    const float* __restrict__ x177, const float* __restrict__ gate,
    unsigned short* __restrict__ gbf) {
  __shared__ __align__(16) unsigned short s_t[HW_ * TSS_];  // [49][72] bf16
  __shared__ float s_g[CCH_];
  int cc = blockIdx.x, b = blockIdx.y, tid = threadIdx.x;
  int c0 = cc * CCH_;
  int valid_c = (c0 + CCH_ <= C_) ? CCH_ : (C_ - c0);   // 64 or 56 (chunk 6)

  unsigned* zt = (unsigned*)s_t;
  for (int i = tid; i < HW_ * TSS_ / 2; i += 256) zt[i] = 0u;
  if (tid < CCH_) {
    int c = c0 + tid;
    s_g[tid] = (c < C_) ? gate[b * C_ + c] : 0.f;
  }
  __syncthreads();

  const f4* xp = (const f4*)(x177 + (size_t)b * (C_ * HW_) + (size_t)c0 * HW_);
  int nvec = valid_c * HW_ / 4;   // 784 or 686 (both exact)
  for (int it = 0; it < 4; ++it) {
    int idx = it * 256 + tid;
    if (idx < nvec) {
      f4 v = xp[idx];
      int e = idx * 4;
      #pragma unroll
      for (int j = 0; j < 4; ++j) {
        int ej = e + j;
        int cl = ej / HW_, hw = ej - cl * HW_;
        s_t[hw * TSS_ + cl] = f2bf(v[j] * s_g[cl]);
      }
    }
  }
  __syncthreads();

  unsigned short* gp = gbf + (size_t)b * HW_ * KP_ + c0;
  for (int it = 0; it < 2; ++it) {
    int p = it * 256 + tid;
    if (p < HW_ * (CCH_ / 8)) {
      int hw = p >> 3, cg = p & 7;
      *(bf8*)(gp + hw * KP_ + cg * 8) = *(const bf8*)(s_t + hw * TSS_ + cg * 8);
    }
  }
}

// ---- K3: y[o][m] = sum_c w3[o][c]*g[m][c], bf16 MFMA, 2-phase prefetch ----
__global__ __launch_bounds__(256) void k_gemm(const unsigned short* __restrict__ w3bf,
                                              const unsigned short* __restrict__ gbf,
                                              float* __restrict__ y) {
  // [buf][ A 128x32 | B 128x32 ] shorts: 2 * 8192 shorts = 32 KB
  __shared__ __align__(16) unsigned short lds[2 * 8192];
  int tid = threadIdx.x, lane = tid & 63, wv = tid >> 6;
  // XCD-aware bijective chunked swizzle (784 = 8 * 98): the 4 consecutive
  // swz (same m-tile, 4 o-tiles) land in one XCD chunk -> gbf L2 reuse.
  int bid0 = blockIdx.x;
  int bid = (bid0 & 7) * 98 + (bid0 >> 3);
  int o0 = (bid & 3) * 128;        // 4 o-tiles (OP_=512)
  int m0 = (bid >> 2) * 128;       // 196 m-tiles
  int wr = wv >> 1, wc = wv & 1;   // wave -> 64x64 quadrant
  f4 acc[4][4] = {};
  const char* Ab = (const char*)w3bf;  // row stride 896 B
  const char* Bb = (const char*)gbf;   // row stride 896 B
  int q0 = wv * 64 + lane;

  // stage K-step kt into buffer buf (A: 8KB, B: 8KB). LDS dest wave-uniform.
  auto stage = [&](int buf, int kt) {
    int k0b = kt * 64;
    char* base = (char*)(lds + buf * 8192);
    #pragma unroll
    for (int i = 0; i < 2; ++i) {
      int q = q0 + i * 256;
      int r = q >> 2, cc = (q & 3) * 16;
      gld16(Ab + (size_t)(o0 + r) * 896 + k0b + cc, base + (wv * 64 + i * 256) * 16);
      gld16(Bb + (size_t)(m0 + r) * 896 + k0b + cc, base + 8192 + (wv * 64 + i * 256) * 16);
    }
  };

  stage(0, 0);
  asm volatile("s_waitcnt vmcnt(0)" ::: "memory");
  __builtin_amdgcn_s_barrier();

  int kg = (lane >> 4) * 8, rl = lane & 15;
  for (int kt = 0; kt < NT_; ++kt) {
    int cur = kt & 1;
    if (kt + 1 < NT_) stage(cur ^ 1, kt + 1);   // prefetch next tile

    const unsigned short* base = lds + cur * 8192;
    bf8 a[4], bb[4];
    #pragma unroll
    for (int i = 0; i < 4; ++i)
      a[i] = *(const bf8*)(base + (wr * 64 + i * 16 + rl) * 32 + kg);
    #pragma unroll
    for (int j = 0; j < 4; ++j)
      bb[j] = *(const bf8*)(base + 4096 + (wc * 64 + j * 16 + rl) * 32 + kg);
    #pragma unroll
    for (int i = 0; i < 4; ++i)
      #pragma unroll
      for (int j = 0; j < 4; ++j)
        acc[i][j] = __builtin_amdgcn_mfma_f32_16x16x32_bf16(a[i], bb[j], acc[i][j], 0, 0, 0);

    if (kt + 1 < NT_) {
      asm volatile("s_waitcnt vmcnt(0)" ::: "memory");  // prefetch landed (hid under MFMA)
      __builtin_amdgcn_s_barrier();
    }
  }

  // D layout: col = lane&15 (m), row = (lane>>4)*4 + reg (o)
  int col = lane & 15, r4 = (lane >> 4) * 4;
  #pragma unroll
  for (int i = 0; i < 4; ++i) {
    int ob = o0 + wr * 64 + i * 16 + r4;
    #pragma unroll
    for (int j = 0; j < 4; ++j) {
      int m = m0 + wc * 64 + j * 16 + col;
      #pragma unroll
      for (int r = 0; r < 4; ++r) {
        int o = ob + r;
        if (o < C_) y[(size_t)o * M_ + m] = acc[i][j][r];
      }
    }
  }
}

// ---------------- K4: per-channel mean/var + normalize + scatter ----------------
__global__ __launch_bounds__(256) void k_norm(const float* __restrict__ y,
                                              const float* __restrict__ gamma,
                                              const float* __restrict__ beta,
                                              float* __restrict__ out) {
  __shared__ float rs[4], rq[4];
  __shared__ float s_scale, s_shift;
  int o = blockIdx.x, tid = threadIdx.x, lane = tid & 63, wv = tid >> 6;
  const float4* yr = (const float4*)(y + (size_t)o * M_);
  float sum = 0.f, sq = 0.f;
  for (int i = tid; i < M_ / 4; i += 256) {
    float4 v = yr[i];
    sum += v.x + v.y + v.z + v.w;
    sq  += v.x * v.x + v.y * v.y + v.z * v.z + v.w * v.w;
  }
  #pragma unroll
  for (int off = 32; off; off >>= 1) {
    sum += __shfl_xor(sum, off, 64);
    sq  += __shfl_xor(sq,  off, 64);
  }
  if (lane == 0) { rs[wv] = sum; rq[wv] = sq; }
  __syncthreads();
  if (tid == 0) {
    float S = rs[0] + rs[1] + rs[2] + rs[3];
    float Q = rq[0] + rq[1] + rq[2] + rq[3];
    float mean = S / (float)M_;
    float var  = Q / (float)M_ - mean * mean;
    float sc = gamma[o] * rsqrtf(var + 1e-5f);
    s_scale = sc;
    s_shift = beta[o] - mean * sc;
  }
  __syncthreads();
  float sc = s_scale, sh = s_shift;
  for (int i = tid; i < M_ / 4; i += 256) {
    float4 v = yr[i];
    float vals[4] = {v.x * sc + sh, v.y * sc + sh, v.z * sc + sh, v.w * sc + sh};
    int m = i * 4;
    #pragma unroll
    for (int j = 0; j < 4; ++j) {
      int mm = m + j;
      int bb = mm / HW_, hw = mm - bb * HW_;
      out[(size_t)bb * (C_ * HW_) + o * HW_ + hw] = vals[j];
    }
  }
}

extern "C" void kernel_launch(void* const* d_in, const int* in_sizes, int n_in,
                              void* d_out, int out_size, void* d_ws, size_t ws_size,
                              hipStream_t stream) {
  const float* x178 = (const float*)d_in[0];
  const float* x177 = (const float*)d_in[1];
  const float* w1   = (const float*)d_in[2];
  const float* b1   = (const float*)d_in[3];
  const float* w2   = (const float*)d_in[4];
  const float* b2   = (const float*)d_in[5];
  const float* w3   = (const float*)d_in[6];
  const float* gamma= (const float*)d_in[7];
  const float* beta = (const float*)d_in[8];
  float* out = (float*)d_out;

  char* ws = (char*)d_ws;
  unsigned short* w3bf = (unsigned short*)ws;                        // 512*448*2 = 458752
  unsigned short* gbf  = (unsigned short*)(ws + 458752);             // 25088*448*2 = 22478848
  float* y             = (float*)(ws + 458752 + 22478848);           // 440*25088*4 = 44154880
  float* gate          = y;   // head of y region; consumed before k_gemm writes y

  hipLaunchKernelGGL(k_prep_w3, dim3((OP_ * KP_) / 256), dim3(256), 0, stream, w3, w3bf);
  hipLaunchKernelGGL(k_gate, dim3(B_), dim3(256), 0, stream,
                     x178, w1, b1, w2, b2, gate);
  hipLaunchKernelGGL(k_scatter, dim3(KP_ / CCH_, B_), dim3(256), 0, stream,
                     x177, gate, gbf);
  hipLaunchKernelGGL(k_gemm, dim3((M_ / 128) * (OP_ / 128)), dim3(256), 0, stream,
                     w3bf, gbf, y);
  hipLaunchKernelGGL(k_norm, dim3(C_), dim3(256), 0, stream, y, gamma, beta, out);
}

// Round 7
// 80.287 us; speedup vs baseline: 1.5136x; 1.0696x over previous
//
#include <hip/hip_runtime.h>
#include <hip/hip_bf16.h>
#include <stdint.h>

#define B_   512
#define C_   440
#define CR_  52
#define HW_  49
#define KP_  448          // padded K (=C) to multiple of 32 (= 7*64)
#define OP_  512          // padded O (=C) to multiple of 128
#define M_   25088        // B_*HW_ (= 196*128 exactly)
#define CCH_ 64           // c-chunk per scatter block
#define TSS_ 72           // scatter LDS row stride (shorts)
#define NT_  (KP_ / 32)   // 14 K-steps

typedef __attribute__((ext_vector_type(8))) short bf8;
typedef __attribute__((ext_vector_type(4))) float f4;

__device__ __forceinline__ unsigned short f2bf(float f) {
  union { float f; unsigned u; } v; v.f = f;
  unsigned r = v.u + 0x7FFFu + ((v.u >> 16) & 1u);
  return (unsigned short)(r >> 16);
}

__device__ __forceinline__ void gld16(const void* g, void* l) {
  __builtin_amdgcn_global_load_lds(
      (const __attribute__((address_space(1))) unsigned int*)g,
      (__attribute__((address_space(3))) unsigned int*)l, 16, 0, 0);
}

// ------- K1: w3 fp32 -> bf16 padded [OP_][KP_]; block 0 zeroes gstats -------
__global__ __launch_bounds__(256) void k_prep_w3(const float* __restrict__ w3,
                                                 unsigned short* __restrict__ w3bf,
                                                 float* __restrict__ gstats) {
  int idx = blockIdx.x * 256 + threadIdx.x;      // grid covers 512*448 exactly
  if (blockIdx.x == 0) {
    #pragma unroll
    for (int i = 0; i < 4; ++i) gstats[threadIdx.x + i * 256] = 0.f;  // 2*OP_ floats
  }
  int o = idx / KP_, c = idx - o * KP_;
  float v = (c < C_ && o < C_) ? w3[o * C_ + c] : 0.f;
  w3bf[idx] = f2bf(v);
}

// ---------------- K2a: per-b gate MLP -> gate[b][c] fp32 ----------------
__global__ __launch_bounds__(256) void k_gate(
    const float* __restrict__ x178,
    const float* __restrict__ w1, const float* __restrict__ b1,
    const float* __restrict__ w2, const float* __restrict__ b2,
    float* __restrict__ gate) {
  __shared__ __align__(16) float s_s[C_];
  __shared__ __align__(16) float s_h[CR_ + 12];   // padded to 64 floats (16 f4)
  int b = blockIdx.x, tid = threadIdx.x;

  if (tid < C_ / 4) ((f4*)s_s)[tid] = ((const f4*)(x178 + (size_t)b * C_))[tid];
  if (tid >= 240 && tid < 240 + 16) ((f4*)s_h)[tid - 240] = f4{0.f, 0.f, 0.f, 0.f};
  __syncthreads();

  int r = tid >> 2, q = tid & 3;     // 64 rows x 4 threads (rows 52..63 idle)
  if (r < CR_) {
    const f4* wr = (const f4*)(w1 + (size_t)r * C_);   // 110 f4 per row
    const f4* ss = (const f4*)s_s;
    f4 acc = {0.f, 0.f, 0.f, 0.f};
    #pragma unroll
    for (int j0 = 0; j0 < 28; ++j0) {
      int j = q + j0 * 4;
      if (j < C_ / 4) {
        f4 w = wr[j], x = ss[j];
        acc += w * x;
      }
    }
    float a = acc[0] + acc[1] + acc[2] + acc[3];
    a += __shfl_xor(a, 1, 64);
    a += __shfl_xor(a, 2, 64);
    if (q == 0) s_h[r] = fmaxf(a + b1[r], 0.f);
  }
  __syncthreads();

  for (int c = tid; c < C_; c += 256) {
    const f4* wc = (const f4*)(w2 + (size_t)c * CR_);  // 13 f4 per row
    const f4* hh = (const f4*)s_h;
    f4 acc = {0.f, 0.f, 0.f, 0.f};
    #pragma unroll
    for (int j = 0; j < 13; ++j) acc += wc[j] * hh[j];
    float a = acc[0] + acc[1] + acc[2] + acc[3] + b2[c];
    gate[b * C_ + c] = 1.f / (1.f + __expf(-a));
  }
}

// ------- K2b: gating + bf16 + transpose, one block per (c-chunk, b) -------
__global__ __launch_bounds__(256) void k_scatter(
    const float* __restrict__ x177, const float* __restrict__ gate,
    unsigned short* __restrict__ gbf) {
  __shared__ __align__(16) unsigned short s_t[HW_ * TSS_];  // [49][72] bf16
  __shared__ float s_g[CCH_];
  int cc = blockIdx.x, b = blockIdx.y, tid = threadIdx.x;
  int c0 = cc * CCH_;
  int valid_c = (c0 + CCH_ <= C_) ? CCH_ : (C_ - c0);   // 64 or 56 (chunk 6)

  unsigned* zt = (unsigned*)s_t;
  for (int i = tid; i < HW_ * TSS_ / 2; i += 256) zt[i] = 0u;
  if (tid < CCH_) {
    int c = c0 + tid;
    s_g[tid] = (c < C_) ? gate[b * C_ + c] : 0.f;
  }
  __syncthreads();

  const f4* xp = (const f4*)(x177 + (size_t)b * (C_ * HW_) + (size_t)c0 * HW_);
  int nvec = valid_c * HW_ / 4;   // 784 or 686 (both exact)
  for (int it = 0; it < 4; ++it) {
    int idx = it * 256 + tid;
    if (idx < nvec) {
      f4 v = xp[idx];
      int e = idx * 4;
      #pragma unroll
      for (int j = 0; j < 4; ++j) {
        int ej = e + j;
        int cl = ej / HW_, hw = ej - cl * HW_;
        s_t[hw * TSS_ + cl] = f2bf(v[j] * s_g[cl]);
      }
    }
  }
  __syncthreads();

  unsigned short* gp = gbf + (size_t)b * HW_ * KP_ + c0;
  for (int it = 0; it < 2; ++it) {
    int p = it * 256 + tid;
    if (p < HW_ * (CCH_ / 8)) {
      int hw = p >> 3, cg = p & 7;
      *(bf8*)(gp + hw * KP_ + cg * 8) = *(const bf8*)(s_t + hw * TSS_ + cg * 8);
    }
  }
}

// ---- K3: y[o][m] = sum_c w3[o][c]*g[m][c] + fused per-channel stats ----
__global__ __launch_bounds__(256) void k_gemm(const unsigned short* __restrict__ w3bf,
                                              const unsigned short* __restrict__ gbf,
                                              float* __restrict__ y,
                                              float* __restrict__ gstats) {
  // [buf][ A 128x32 | B 128x32 ] shorts: 2 * 8192 shorts = 32 KB
  __shared__ __align__(16) unsigned short lds[2 * 8192];
  int tid = threadIdx.x, lane = tid & 63, wv = tid >> 6;
  // XCD-aware bijective chunked swizzle (784 = 8 * 98)
  int bid0 = blockIdx.x;
  int bid = (bid0 & 7) * 98 + (bid0 >> 3);
  int o0 = (bid & 3) * 128;        // 4 o-tiles (OP_=512)
  int m0 = (bid >> 2) * 128;       // 196 m-tiles
  int wr = wv >> 1, wc = wv & 1;   // wave -> 64x64 quadrant
  f4 acc[4][4] = {};
  const char* Ab = (const char*)w3bf;  // row stride 896 B
  const char* Bb = (const char*)gbf;   // row stride 896 B
  int q0 = wv * 64 + lane;

  auto stage = [&](int buf, int kt) {
    int k0b = kt * 64;
    char* base = (char*)(lds + buf * 8192);
    #pragma unroll
    for (int i = 0; i < 2; ++i) {
      int q = q0 + i * 256;
      int r = q >> 2, cc = (q & 3) * 16;
      gld16(Ab + (size_t)(o0 + r) * 896 + k0b + cc, base + (wv * 64 + i * 256) * 16);
      gld16(Bb + (size_t)(m0 + r) * 896 + k0b + cc, base + 8192 + (wv * 64 + i * 256) * 16);
    }
  };

  stage(0, 0);
  asm volatile("s_waitcnt vmcnt(0)" ::: "memory");
  __builtin_amdgcn_s_barrier();

  int kg = (lane >> 4) * 8, rl = lane & 15;
  for (int kt = 0; kt < NT_; ++kt) {
    int cur = kt & 1;
    if (kt + 1 < NT_) stage(cur ^ 1, kt + 1);   // prefetch next tile

    const unsigned short* base = lds + cur * 8192;
    bf8 a[4], bb[4];
    #pragma unroll
    for (int i = 0; i < 4; ++i)
      a[i] = *(const bf8*)(base + (wr * 64 + i * 16 + rl) * 32 + kg);
    #pragma unroll
    for (int j = 0; j < 4; ++j)
      bb[j] = *(const bf8*)(base + 4096 + (wc * 64 + j * 16 + rl) * 32 + kg);
    #pragma unroll
    for (int i = 0; i < 4; ++i)
      #pragma unroll
      for (int j = 0; j < 4; ++j)
        acc[i][j] = __builtin_amdgcn_mfma_f32_16x16x32_bf16(a[i], bb[j], acc[i][j], 0, 0, 0);

    if (kt + 1 < NT_) {
      asm volatile("s_waitcnt vmcnt(0)" ::: "memory");
      __builtin_amdgcn_s_barrier();
    }
  }

  // D layout: col = lane&15 (m), row = (lane>>4)*4 + reg (o)
  int col = lane & 15, r4 = (lane >> 4) * 4;
  #pragma unroll
  for (int i = 0; i < 4; ++i) {
    int ob = o0 + wr * 64 + i * 16 + r4;
    #pragma unroll
    for (int j = 0; j < 4; ++j) {
      int m = m0 + wc * 64 + j * 16 + col;
      #pragma unroll
      for (int r = 0; r < 4; ++r) {
        int o = ob + r;
        if (o < C_) y[(size_t)o * M_ + m] = acc[i][j][r];
      }
    }
  }

  // ---- fused stats: per-block sum/sumsq over this block's 128 m-cols ----
  __syncthreads();                      // all LDS reads of the K-loop done
  float* part = (float*)lds;            // [128 o-rows][2 wc][2 {sum,sq}] = 2 KB
  #pragma unroll
  for (int i = 0; i < 4; ++i) {
    float s[4], q[4];
    #pragma unroll
    for (int r = 0; r < 4; ++r) {
      float ss = 0.f, qq = 0.f;
      #pragma unroll
      for (int j = 0; j < 4; ++j) { float v = acc[i][j][r]; ss += v; qq += v * v; }
      s[r] = ss; q[r] = qq;
    }
    #pragma unroll
    for (int off = 1; off < 16; off <<= 1) {
      #pragma unroll
      for (int r = 0; r < 4; ++r) {
        s[r] += __shfl_xor(s[r], off, 64);
        q[r] += __shfl_xor(q[r], off, 64);
      }
    }
    if ((lane & 15) == 0) {
      int row = wr * 64 + i * 16 + (lane >> 4) * 4;
      #pragma unroll
      for (int r = 0; r < 4; ++r) {
        part[(row + r) * 4 + wc * 2 + 0] = s[r];
        part[(row + r) * 4 + wc * 2 + 1] = q[r];
      }
    }
  }
  __syncthreads();
  {
    int row = tid >> 1, which = tid & 1;          // 256 threads = 128 rows x 2
    float v = part[row * 4 + which] + part[row * 4 + 2 + which];
    int o = o0 + row;
    if (o < C_) atomicAdd(&gstats[o * 2 + which], v);
  }
}

// -------- K4: single-pass normalize y -> out using fused gstats --------
__global__ __launch_bounds__(256) void k_norm(const float* __restrict__ y,
                                              const float* __restrict__ gstats,
                                              const float* __restrict__ gamma,
                                              const float* __restrict__ beta,
                                              float* __restrict__ out) {
  int o = blockIdx.x, seg = blockIdx.y, tid = threadIdx.x;
  float S = gstats[o * 2 + 0], Q = gstats[o * 2 + 1];
  float mean = S * (1.f / (float)M_);
  float var  = Q * (1.f / (float)M_) - mean * mean;
  float sc = gamma[o] * rsqrtf(var + 1e-5f);
  float sh = beta[o] - mean * sc;
  const f4* yr = (const f4*)(y + (size_t)o * M_ + (size_t)seg * (M_ / 4));
  for (int i = tid; i < M_ / 16; i += 256) {       // 1568 f4 per segment
    f4 v = yr[i];
    int m = seg * (M_ / 4) + i * 4;
    #pragma unroll
    for (int j = 0; j < 4; ++j) {
      int mm = m + j;
      int bb = mm / HW_, hw = mm - bb * HW_;
      out[(size_t)bb * (C_ * HW_) + o * HW_ + hw] = v[j] * sc + sh;
    }
  }
}

extern "C" void kernel_launch(void* const* d_in, const int* in_sizes, int n_in,
                              void* d_out, int out_size, void* d_ws, size_t ws_size,
                              hipStream_t stream) {
  const float* x178 = (const float*)d_in[0];
  const float* x177 = (const float*)d_in[1];
  const float* w1   = (const float*)d_in[2];
  const float* b1   = (const float*)d_in[3];
  const float* w2   = (const float*)d_in[4];
  const float* b2   = (const float*)d_in[5];
  const float* w3   = (const float*)d_in[6];
  const float* gamma= (const float*)d_in[7];
  const float* beta = (const float*)d_in[8];
  float* out = (float*)d_out;

  char* ws = (char*)d_ws;
  unsigned short* w3bf = (unsigned short*)ws;                        // 512*448*2 = 458752
  unsigned short* gbf  = (unsigned short*)(ws + 458752);             // 25088*448*2 = 22478848
  float* y             = (float*)(ws + 458752 + 22478848);           // 440*25088*4 = 44154880
  float* gstats        = (float*)(ws + 458752 + 22478848 + 44154880); // 2*512*4 = 4096
  float* gate          = y;   // head of y region; consumed before k_gemm writes y

  hipLaunchKernelGGL(k_prep_w3, dim3((OP_ * KP_) / 256), dim3(256), 0, stream,
                     w3, w3bf, gstats);
  hipLaunchKernelGGL(k_gate, dim3(B_), dim3(256), 0, stream,
                     x178, w1, b1, w2, b2, gate);
  hipLaunchKernelGGL(k_scatter, dim3(KP_ / CCH_, B_), dim3(256), 0, stream,
                     x177, gate, gbf);
  hipLaunchKernelGGL(k_gemm, dim3((M_ / 128) * (OP_ / 128)), dim3(256), 0, stream,
                     w3bf, gbf, y, gstats);
  hipLaunchKernelGGL(k_norm, dim3(C_, 4), dim3(256), 0, stream,
                     y, gstats, gamma, beta, out);
}

// Round 8
// 80.133 us; speedup vs baseline: 1.5166x; 1.0019x over previous
//
#include <hip/hip_runtime.h>
#include <hip/hip_bf16.h>
#include <stdint.h>

#define B_   512
#define C_   440
#define CR_  52
#define HW_  49
#define KP_  448          // padded K (=C) to multiple of 32 (= 7*64)
#define OP_  512          // padded O (=C) to multiple of 128
#define M_   25088        // B_*HW_ (= 196*128 exactly)
#define CCH_ 64           // c-chunk per scatter block
#define TSS_ 72           // scatter LDS row stride (shorts)
#define NT_  14           // K-steps (448/32)

typedef __attribute__((ext_vector_type(8))) short bf8;
typedef __attribute__((ext_vector_type(4))) float f4;

__device__ __forceinline__ unsigned short f2bf(float f) {
  union { float f; unsigned u; } v; v.f = f;
  unsigned r = v.u + 0x7FFFu + ((v.u >> 16) & 1u);
  return (unsigned short)(r >> 16);
}

__device__ __forceinline__ void gld16(const void* g, void* l) {
  __builtin_amdgcn_global_load_lds(
      (const __attribute__((address_space(1))) unsigned int*)g,
      (__attribute__((address_space(3))) unsigned int*)l, 16, 0, 0);
}

// ------- K1: w3 fp32 -> bf16 padded [OP_][KP_]; block 0 zeroes gstats -------
__global__ __launch_bounds__(256) void k_prep_w3(const float* __restrict__ w3,
                                                 unsigned short* __restrict__ w3bf,
                                                 float* __restrict__ gstats) {
  int idx = blockIdx.x * 256 + threadIdx.x;      // grid covers 512*448 exactly
  if (blockIdx.x == 0) {
    #pragma unroll
    for (int i = 0; i < 4; ++i) gstats[threadIdx.x + i * 256] = 0.f;  // 2*OP_ floats
  }
  int o = idx / KP_, c = idx - o * KP_;
  float v = (c < C_ && o < C_) ? w3[o * C_ + c] : 0.f;
  w3bf[idx] = f2bf(v);
}

// ---------------- K2a: per-b gate MLP -> gate[b][c] fp32 ----------------
__global__ __launch_bounds__(256) void k_gate(
    const float* __restrict__ x178,
    const float* __restrict__ w1, const float* __restrict__ b1,
    const float* __restrict__ w2, const float* __restrict__ b2,
    float* __restrict__ gate) {
  __shared__ __align__(16) float s_s[C_];
  __shared__ __align__(16) float s_h[CR_ + 12];   // padded to 64 floats (16 f4)
  int b = blockIdx.x, tid = threadIdx.x;

  if (tid < C_ / 4) ((f4*)s_s)[tid] = ((const f4*)(x178 + (size_t)b * C_))[tid];
  if (tid >= 240 && tid < 240 + 16) ((f4*)s_h)[tid - 240] = f4{0.f, 0.f, 0.f, 0.f};
  __syncthreads();

  int r = tid >> 2, q = tid & 3;     // 64 rows x 4 threads (rows 52..63 idle)
  if (r < CR_) {
    const f4* wr = (const f4*)(w1 + (size_t)r * C_);   // 110 f4 per row
    const f4* ss = (const f4*)s_s;
    f4 acc = {0.f, 0.f, 0.f, 0.f};
    #pragma unroll
    for (int j0 = 0; j0 < 28; ++j0) {
      int j = q + j0 * 4;
      if (j < C_ / 4) {
        f4 w = wr[j], x = ss[j];
        acc += w * x;
      }
    }
    float a = acc[0] + acc[1] + acc[2] + acc[3];
    a += __shfl_xor(a, 1, 64);
    a += __shfl_xor(a, 2, 64);
    if (q == 0) s_h[r] = fmaxf(a + b1[r], 0.f);
  }
  __syncthreads();

  for (int c = tid; c < C_; c += 256) {
    const f4* wc = (const f4*)(w2 + (size_t)c * CR_);  // 13 f4 per row
    const f4* hh = (const f4*)s_h;
    f4 acc = {0.f, 0.f, 0.f, 0.f};
    #pragma unroll
    for (int j = 0; j < 13; ++j) acc += wc[j] * hh[j];
    float a = acc[0] + acc[1] + acc[2] + acc[3] + b2[c];
    gate[b * C_ + c] = 1.f / (1.f + __expf(-a));
  }
}

// ------- K2b: gating + bf16 + transpose, one block per (c-chunk, b) -------
__global__ __launch_bounds__(256) void k_scatter(
    const float* __restrict__ x177, const float* __restrict__ gate,
    unsigned short* __restrict__ gbf) {
  __shared__ __align__(16) unsigned short s_t[HW_ * TSS_];  // [49][72] bf16
  __shared__ float s_g[CCH_];
  int cc = blockIdx.x, b = blockIdx.y, tid = threadIdx.x;
  int c0 = cc * CCH_;
  int valid_c = (c0 + CCH_ <= C_) ? CCH_ : (C_ - c0);   // 64 or 56 (chunk 6)

  unsigned* zt = (unsigned*)s_t;
  for (int i = tid; i < HW_ * TSS_ / 2; i += 256) zt[i] = 0u;
  if (tid < CCH_) {
    int c = c0 + tid;
    s_g[tid] = (c < C_) ? gate[b * C_ + c] : 0.f;
  }
  __syncthreads();

  const f4* xp = (const f4*)(x177 + (size_t)b * (C_ * HW_) + (size_t)c0 * HW_);
  int nvec = valid_c * HW_ / 4;   // 784 or 686 (both exact)
  for (int it = 0; it < 4; ++it) {
    int idx = it * 256 + tid;
    if (idx < nvec) {
      f4 v = xp[idx];
      int e = idx * 4;
      #pragma unroll
      for (int j = 0; j < 4; ++j) {
        int ej = e + j;
        int cl = ej / HW_, hw = ej - cl * HW_;
        s_t[hw * TSS_ + cl] = f2bf(v[j] * s_g[cl]);
      }
    }
  }
  __syncthreads();

  unsigned short* gp = gbf + (size_t)b * HW_ * KP_ + c0;
  for (int it = 0; it < 2; ++it) {
    int p = it * 256 + tid;
    if (p < HW_ * (CCH_ / 8)) {
      int hw = p >> 3, cg = p & 7;
      *(bf8*)(gp + hw * KP_ + cg * 8) = *(const bf8*)(s_t + hw * TSS_ + cg * 8);
    }
  }
}

// ---- K3: y[o][m] = sum_c w3[o][c]*g[m][c], 3-slot counted-vmcnt pipeline ----
__global__ __launch_bounds__(256, 3) void k_gemm(const unsigned short* __restrict__ w3bf,
                                                 const unsigned short* __restrict__ gbf,
                                                 float* __restrict__ y,
                                                 float* __restrict__ gstats) {
  // 3 slots x [ A 128x32 | B 128x32 ] shorts = 48 KB
  __shared__ __align__(16) unsigned short lds[3 * 8192];
  int tid = threadIdx.x, lane = tid & 63, wv = tid >> 6;
  // XCD-aware bijective chunked swizzle (784 = 8 * 98)
  int bid0 = blockIdx.x;
  int bid = (bid0 & 7) * 98 + (bid0 >> 3);
  int o0 = (bid & 3) * 128;        // 4 o-tiles (OP_=512)
  int m0 = (bid >> 2) * 128;       // 196 m-tiles
  int wr = wv >> 1, wc = wv & 1;   // wave -> 64x64 quadrant
  f4 acc[4][4] = {};
  const char* Ab = (const char*)w3bf;  // row stride 896 B
  const char* Bb = (const char*)gbf;   // row stride 896 B
  int q0 = wv * 64 + lane;

  // stage K-step kt into slot (4 gld16 per wave -> vmcnt units of 4)
  auto stage = [&](int slot, int kt) {
    int k0b = kt * 64;
    char* base = (char*)(lds + slot * 8192);
    #pragma unroll
    for (int i = 0; i < 2; ++i) {
      int q = q0 + i * 256;
      int r = q >> 2, cc = (q & 3) * 16;
      gld16(Ab + (size_t)(o0 + r) * 896 + k0b + cc, base + (wv * 64 + i * 256) * 16);
      gld16(Bb + (size_t)(m0 + r) * 896 + k0b + cc, base + 8192 + (wv * 64 + i * 256) * 16);
    }
  };

  stage(0, 0);
  stage(1, 1);

  int kg = (lane >> 4) * 8, rl = lane & 15;
  int slot = 0;
  for (int kt = 0; kt < NT_; ++kt) {
    // wait: stage kt landed (4 instrs of stage kt+1 may stay in flight)
    if (kt + 1 < NT_) asm volatile("s_waitcnt vmcnt(4)" ::: "memory");
    else              asm volatile("s_waitcnt vmcnt(0)" ::: "memory");
    __builtin_amdgcn_s_barrier();   // all waves' stage-kt chunks visible;
                                    // all waves done reading slot (kt-1)%3

    const unsigned short* base = lds + slot * 8192;
    bf8 a[4], bb[4];
    #pragma unroll
    for (int i = 0; i < 4; ++i)
      a[i] = *(const bf8*)(base + (wr * 64 + i * 16 + rl) * 32 + kg);
    #pragma unroll
    for (int j = 0; j < 4; ++j)
      bb[j] = *(const bf8*)(base + 4096 + (wc * 64 + j * 16 + rl) * 32 + kg);

    if (kt + 2 < NT_) {
      int s2 = slot + 2; if (s2 >= 3) s2 -= 3;
      stage(s2, kt + 2);            // overwrites slot of kt-1 (reads retired)
    }

    #pragma unroll
    for (int i = 0; i < 4; ++i)
      #pragma unroll
      for (int j = 0; j < 4; ++j)
        acc[i][j] = __builtin_amdgcn_mfma_f32_16x16x32_bf16(a[i], bb[j], acc[i][j], 0, 0, 0);

    if (++slot == 3) slot = 0;
  }

  // D layout: col = lane&15 (m), row = (lane>>4)*4 + reg (o)
  int col = lane & 15, r4 = (lane >> 4) * 4;
  #pragma unroll
  for (int i = 0; i < 4; ++i) {
    int ob = o0 + wr * 64 + i * 16 + r4;
    #pragma unroll
    for (int j = 0; j < 4; ++j) {
      int m = m0 + wc * 64 + j * 16 + col;
      #pragma unroll
      for (int r = 0; r < 4; ++r) {
        int o = ob + r;
        if (o < C_) y[(size_t)o * M_ + m] = acc[i][j][r];
      }
    }
  }

  // ---- fused stats: per-block sum/sumsq over this block's 128 m-cols ----
  __syncthreads();                      // all LDS reads of the K-loop done
  float* part = (float*)lds;            // [128 o-rows][2 wc][2 {sum,sq}] = 2 KB
  #pragma unroll
  for (int i = 0; i < 4; ++i) {
    float s[4], q[4];
    #pragma unroll
    for (int r = 0; r < 4; ++r) {
      float ss = 0.f, qq = 0.f;
      #pragma unroll
      for (int j = 0; j < 4; ++j) { float v = acc[i][j][r]; ss += v; qq += v * v; }
      s[r] = ss; q[r] = qq;
    }
    #pragma unroll
    for (int off = 1; off < 16; off <<= 1) {
      #pragma unroll
      for (int r = 0; r < 4; ++r) {
        s[r] += __shfl_xor(s[r], off, 64);
        q[r] += __shfl_xor(q[r], off, 64);
      }
    }
    if ((lane & 15) == 0) {
      int row = wr * 64 + i * 16 + (lane >> 4) * 4;
      #pragma unroll
      for (int r = 0; r < 4; ++r) {
        part[(row + r) * 4 + wc * 2 + 0] = s[r];
        part[(row + r) * 4 + wc * 2 + 1] = q[r];
      }
    }
  }
  __syncthreads();
  {
    int row = tid >> 1, which = tid & 1;          // 256 threads = 128 rows x 2
    float v = part[row * 4 + which] + part[row * 4 + 2 + which];
    int o = o0 + row;
    if (o < C_) atomicAdd(&gstats[o * 2 + which], v);
  }
}

// -------- K4: single-pass normalize y -> out using fused gstats --------
__global__ __launch_bounds__(256) void k_norm(const float* __restrict__ y,
                                              const float* __restrict__ gstats,
                                              const float* __restrict__ gamma,
                                              const float* __restrict__ beta,
                                              float* __restrict__ out) {
  int o = blockIdx.x, seg = blockIdx.y, tid = threadIdx.x;
  float S = gstats[o * 2 + 0], Q = gstats[o * 2 + 1];
  float mean = S * (1.f / (float)M_);
  float var  = Q * (1.f / (float)M_) - mean * mean;
  float sc = gamma[o] * rsqrtf(var + 1e-5f);
  float sh = beta[o] - mean * sc;
  const f4* yr = (const f4*)(y + (size_t)o * M_ + (size_t)seg * (M_ / 4));
  for (int i = tid; i < M_ / 16; i += 256) {       // 1568 f4 per segment
    f4 v = yr[i];
    int m = seg * (M_ / 4) + i * 4;
    #pragma unroll
    for (int j = 0; j < 4; ++j) {
      int mm = m + j;
      int bb = mm / HW_, hw = mm - bb * HW_;
      out[(size_t)bb * (C_ * HW_) + o * HW_ + hw] = v[j] * sc + sh;
    }
  }
}

extern "C" void kernel_launch(void* const* d_in, const int* in_sizes, int n_in,
                              void* d_out, int out_size, void* d_ws, size_t ws_size,
                              hipStream_t stream) {
  const float* x178 = (const float*)d_in[0];
  const float* x177 = (const float*)d_in[1];
  const float* w1   = (const float*)d_in[2];
  const float* b1   = (const float*)d_in[3];
  const float* w2   = (const float*)d_in[4];
  const float* b2   = (const float*)d_in[5];
  const float* w3   = (const float*)d_in[6];
  const float* gamma= (const float*)d_in[7];
  const float* beta = (const float*)d_in[8];
  float* out = (float*)d_out;

  char* ws = (char*)d_ws;
  unsigned short* w3bf = (unsigned short*)ws;                        // 512*448*2 = 458752
  unsigned short* gbf  = (unsigned short*)(ws + 458752);             // 25088*448*2 = 22478848
  float* y             = (float*)(ws + 458752 + 22478848);           // 440*25088*4 = 44154880
  float* gstats        = (float*)(ws + 458752 + 22478848 + 44154880); // 2*512*4 = 4096
  float* gate          = y;   // head of y region; consumed before k_gemm writes y

  hipLaunchKernelGGL(k_prep_w3, dim3((OP_ * KP_) / 256), dim3(256), 0, stream,
                     w3, w3bf, gstats);
  hipLaunchKernelGGL(k_gate, dim3(B_), dim3(256), 0, stream,
                     x178, w1, b1, w2, b2, gate);
  hipLaunchKernelGGL(k_scatter, dim3(KP_ / CCH_, B_), dim3(256), 0, stream,
                     x177, gate, gbf);
  hipLaunchKernelGGL(k_gemm, dim3((M_ / 128) * (OP_ / 128)), dim3(256), 0, stream,
                     w3bf, gbf, y, gstats);
  hipLaunchKernelGGL(k_norm, dim3(C_, 4), dim3(256), 0, stream,
                     y, gstats, gamma, beta, out);
}